// Round 3
// baseline (119.419 us; speedup 1.0000x reference)
//
#include <hip/hip_runtime.h>

#define M 256
#define N 768
#define K 768

#define TI 4          // output rows per block (in registers)
#define TJ 192        // output cols per block (one thread per col per k-slice)
#define KP 4          // k-partitions
#define KCH (K / KP)  // 192 k per partition
#define NTHREADS (TJ * KP)  // 768

// ws layout (bytes):
//   [0..7]   : two u32 absmax bit-patterns (|x| max, |w| max)
//   [256 ..) : xiT  — quantized x, transposed+packed: xiT[k*256 + row], 768*256 B
//   [196864..): wi  — quantized w row-major [j][k], 768*768 B
#define WS_OFF_XIT 256
#define WS_OFF_WI  196864

#define SMEM_LUT   131072                 // 65536 x int16
#define SMEM_XI    (SMEM_LUT)             // 768 dwords (packed xi for 4 rows)
#define SMEM_RED   (SMEM_LUT + 3072)      // 768*4 int32 partials
#define SMEM_BYTES (SMEM_LUT + 3072 + 12288)  // 146432

__global__ void absmax_kernel(const float* __restrict__ x,
                              const float* __restrict__ w,
                              unsigned* __restrict__ wsmax) {
    int tid = blockIdx.x * blockDim.x + threadIdx.x;
    int stride = gridDim.x * blockDim.x;
    float mx = 0.f, mw = 0.f;
    const float4* x4 = (const float4*)x;
    const float4* w4 = (const float4*)w;
    for (int i = tid; i < (M * K) / 4; i += stride) {
        float4 v = x4[i];
        mx = fmaxf(mx, fmaxf(fmaxf(fabsf(v.x), fabsf(v.y)),
                             fmaxf(fabsf(v.z), fabsf(v.w))));
    }
    for (int i = tid; i < (N * K) / 4; i += stride) {
        float4 v = w4[i];
        mw = fmaxf(mw, fmaxf(fmaxf(fabsf(v.x), fabsf(v.y)),
                             fmaxf(fabsf(v.z), fabsf(v.w))));
    }
    #pragma unroll
    for (int off = 32; off > 0; off >>= 1) {
        mx = fmaxf(mx, __shfl_down(mx, off, 64));
        mw = fmaxf(mw, __shfl_down(mw, off, 64));
    }
    if ((threadIdx.x & 63) == 0) {
        atomicMax(&wsmax[0], __float_as_uint(mx));   // valid: all values >= 0
        atomicMax(&wsmax[1], __float_as_uint(mw));
    }
}

__global__ void quant_kernel(const float* __restrict__ x,
                             const float* __restrict__ w,
                             unsigned char* __restrict__ wsb,
                             const unsigned* __restrict__ wsmax) {
    float sx = __uint_as_float(wsmax[0]) / 127.f;
    float sw = __uint_as_float(wsmax[1]) / 127.f;
    unsigned char* xiT = wsb + WS_OFF_XIT;
    unsigned char* wi  = wsb + WS_OFF_WI;
    int tid = blockIdx.x * blockDim.x + threadIdx.x;
    int stride = gridDim.x * blockDim.x;
    for (int e = tid; e < M * K; e += stride) {
        float q = rintf(x[e] / sx);               // IEEE div + half-even, matches numpy
        q = fminf(fmaxf(q, -127.f), 127.f);
        int row = e / K;
        int k = e - row * K;
        xiT[k * 256 + row] = (unsigned char)((int)q + 128);
    }
    for (int e = tid; e < N * K; e += stride) {
        float q = rintf(w[e] / sw);
        q = fminf(fmaxf(q, -127.f), 127.f);
        wi[e] = (unsigned char)((int)q + 128);
    }
}

__global__ void __launch_bounds__(NTHREADS, 1)
lutmm_kernel(const int* __restrict__ lut,
             const float* __restrict__ bias,
             const unsigned char* __restrict__ wsb,
             const unsigned* __restrict__ wsmax,
             float* __restrict__ out) {
    extern __shared__ char smem[];
    short*    lutS = (short*)smem;                    // 65536 int16
    unsigned* xiS  = (unsigned*)(smem + SMEM_XI);     // 768 packed dwords
    int*      red  = (int*)(smem + SMEM_RED);         // 768*4 partials

    const int tid  = threadIdx.x;
    const int row0 = blockIdx.x * TI;
    const int col0 = blockIdx.y * TJ;

    // LUT int32 -> int16 into LDS (values fit: |prod+noise| <= 16392)
    const int4* lut4 = (const int4*)lut;
    for (int idx = tid; idx < 65536 / 4; idx += NTHREADS) {
        int4 v = lut4[idx];
        unsigned lo = ((unsigned)v.x & 0xFFFFu) | ((unsigned)v.y << 16);
        unsigned hi = ((unsigned)v.z & 0xFFFFu) | ((unsigned)v.w << 16);
        ((uint2*)lutS)[idx] = make_uint2(lo, hi);
    }

    // packed xi for this block's 4 rows: one dword per k (wave-uniform reads later)
    const unsigned char* xiT = wsb + WS_OFF_XIT;
    for (int t = tid; t < K; t += NTHREADS) {
        xiS[t] = *(const unsigned*)(xiT + t * 256 + row0);
    }
    __syncthreads();

    const int kp = tid / TJ;         // wave-uniform (TJ = 192 = 3 waves)
    const int j  = tid - kp * TJ;
    const int k0 = kp * KCH;
    const unsigned char* wrow = wsb + WS_OFF_WI + (size_t)(col0 + j) * K + k0;

    int acc0 = 0, acc1 = 0, acc2 = 0, acc3 = 0;
    for (int kk = 0; kk < KCH; kk += 16) {
        uint4 wv = *(const uint4*)(wrow + kk);
        const unsigned* wp = (const unsigned*)&wv;
        const unsigned* xp = &xiS[k0 + kk];
        #pragma unroll
        for (int u = 0; u < 16; ++u) {
            unsigned wb = (wp[u >> 2] >> ((u & 3) * 8)) & 255u;
            unsigned xd = xp[u];     // broadcast (uniform within wave)
            acc0 += lutS[((xd & 255u) << 8) + wb];
            acc1 += lutS[(((xd >> 8) & 255u) << 8) + wb];
            acc2 += lutS[(((xd >> 16) & 255u) << 8) + wb];
            acc3 += lutS[((xd >> 24) << 8) + wb];
        }
    }

    red[tid * TI + 0] = acc0;
    red[tid * TI + 1] = acc1;
    red[tid * TI + 2] = acc2;
    red[tid * TI + 3] = acc3;
    __syncthreads();

    // epilogue: thread t -> output (row0 + i, col0 + j2)
    const int i  = tid / TJ;
    const int j2 = tid - i * TJ;
    int s = 0;
    #pragma unroll
    for (int kp2 = 0; kp2 < KP; ++kp2) {
        s += red[(kp2 * TJ + j2) * TI + i];
    }
    float sx = __uint_as_float(wsmax[0]) / 127.f;
    float sw = __uint_as_float(wsmax[1]) / 127.f;
    out[(row0 + i) * N + col0 + j2] = (float)s * (sx * sw) + bias[col0 + j2];
}

extern "C" void kernel_launch(void* const* d_in, const int* in_sizes, int n_in,
                              void* d_out, int out_size, void* d_ws, size_t ws_size,
                              hipStream_t stream) {
    const float* x    = (const float*)d_in[0];
    const float* w    = (const float*)d_in[1];
    const float* bias = (const float*)d_in[2];
    const int*   lut  = (const int*)d_in[3];
    float* out = (float*)d_out;
    unsigned* wsmax = (unsigned*)d_ws;
    unsigned char* wsb = (unsigned char*)d_ws;

    hipMemsetAsync(d_ws, 0, 8, stream);
    absmax_kernel<<<256, 256, 0, stream>>>(x, w, wsmax);
    quant_kernel<<<512, 256, 0, stream>>>(x, w, wsb, wsmax);
    hipFuncSetAttribute((const void*)lutmm_kernel,
                        hipFuncAttributeMaxDynamicSharedMemorySize, SMEM_BYTES);
    lutmm_kernel<<<dim3(M / TI, N / TJ), NTHREADS, SMEM_BYTES, stream>>>(
        lut, bias, wsb, wsmax, out);
}

// Round 4
// 92.785 us; speedup vs baseline: 1.2870x; 1.2870x over previous
//
#include <hip/hip_runtime.h>

#define M 256
#define N 768
#define K 768

// ws layout (bytes)
#define WS_PARTX 0        // 256 f32 per-block |x| maxes
#define WS_PARTW 1024     // 256 f32 per-block |w| maxes
#define WS_LUT16 4096     // 131072 B: LUT as int16
#define WS_WP    135168   // 589824 B: wP[k4*768 + j] = packed 4 offset-bytes of w[j][4k4..4k4+3]

#define TI 4
#define TJ 192
#define NTH 768

#define SM_LUT 131072
#define SM_XI  (SM_LUT)            // 768 dwords (packed xi, 4 rows per k)
#define SM_RED (SM_LUT + 3072)     // 768*4 int32 partials
#define SM_SC  (SM_RED + 12288)    // 2 floats (sx, sw)
#define SMEM_BYTES (SM_SC + 8)     // 146440

__global__ void absmax_lut_kernel(const float* __restrict__ x,
                                  const float* __restrict__ w,
                                  const int* __restrict__ lut,
                                  unsigned char* __restrict__ wsb) {
    const int tid = threadIdx.x, bid = blockIdx.x;
    // LUT int32 -> int16 (values fit: |prod+noise| <= 16137): 256 entries/block
    if (tid < 128) {
        int e = bid * 128 + tid;
        int2 v = ((const int2*)lut)[e];
        ((unsigned*)(wsb + WS_LUT16))[e] =
            ((unsigned)v.x & 0xFFFFu) | ((unsigned)v.y << 16);
    }
    int gid = bid * 256 + tid;
    const int stride = 256 * 256;
    float mx = 0.f, mw = 0.f;
    const float4* x4 = (const float4*)x;
    const float4* w4 = (const float4*)w;
    for (int i = gid; i < (M * K) / 4; i += stride) {
        float4 v = x4[i];
        mx = fmaxf(mx, fmaxf(fmaxf(fabsf(v.x), fabsf(v.y)),
                             fmaxf(fabsf(v.z), fabsf(v.w))));
    }
    for (int i = gid; i < (N * K) / 4; i += stride) {
        float4 v = w4[i];
        mw = fmaxf(mw, fmaxf(fmaxf(fabsf(v.x), fabsf(v.y)),
                             fmaxf(fabsf(v.z), fabsf(v.w))));
    }
    #pragma unroll
    for (int o = 32; o > 0; o >>= 1) {
        mx = fmaxf(mx, __shfl_down(mx, o, 64));
        mw = fmaxf(mw, __shfl_down(mw, o, 64));
    }
    __shared__ float sred[8];
    if ((tid & 63) == 0) { sred[tid >> 6] = mx; sred[4 + (tid >> 6)] = mw; }
    __syncthreads();
    if (tid == 0) {
        ((float*)(wsb + WS_PARTX))[bid] =
            fmaxf(fmaxf(sred[0], sred[1]), fmaxf(sred[2], sred[3]));
        ((float*)(wsb + WS_PARTW))[bid] =
            fmaxf(fmaxf(sred[4], sred[5]), fmaxf(sred[6], sred[7]));
    }
}

__global__ void wquant_kernel(const float* __restrict__ w,
                              unsigned char* __restrict__ wsb) {
    __shared__ float s_sw;
    const int tid = threadIdx.x;
    const float* partW = (const float*)(wsb + WS_PARTW);
    if (tid < 64) {
        float m = fmaxf(fmaxf(partW[tid], partW[tid + 64]),
                        fmaxf(partW[tid + 128], partW[tid + 192]));
        #pragma unroll
        for (int o = 32; o > 0; o >>= 1) m = fmaxf(m, __shfl_down(m, o, 64));
        if (tid == 0) s_sw = m / 127.f;
    }
    __syncthreads();
    const float sw = s_sw;
    int gid = blockIdx.x * 512 + tid;           // 0..147455, one dword each
    int k4 = gid / 768;
    int j  = gid - k4 * 768;
    float4 v = *(const float4*)(w + j * K + k4 * 4);
    unsigned q0 = (unsigned)((int)fminf(fmaxf(rintf(v.x / sw), -127.f), 127.f) + 128);
    unsigned q1 = (unsigned)((int)fminf(fmaxf(rintf(v.y / sw), -127.f), 127.f) + 128);
    unsigned q2 = (unsigned)((int)fminf(fmaxf(rintf(v.z / sw), -127.f), 127.f) + 128);
    unsigned q3 = (unsigned)((int)fminf(fmaxf(rintf(v.w / sw), -127.f), 127.f) + 128);
    ((unsigned*)(wsb + WS_WP))[gid] = q0 | (q1 << 8) | (q2 << 16) | (q3 << 24);
}

__global__ void __launch_bounds__(NTH, 1)
lutmm_kernel(const float* __restrict__ x,
             const float* __restrict__ bias,
             const unsigned char* __restrict__ wsb,
             float* __restrict__ out) {
    extern __shared__ char smem[];
    short*    lutS = (short*)smem;
    unsigned* xiS  = (unsigned*)(smem + SM_XI);
    int*      red  = (int*)(smem + SM_RED);
    float*    scS  = (float*)(smem + SM_SC);

    const int tid  = threadIdx.x;
    const int row0 = blockIdx.x * TI;
    const int col0 = blockIdx.y * TJ;

    // scales from per-block partials (max is order-independent -> bit-exact)
    if (tid < 64) {
        const float* pX = (const float*)(wsb + WS_PARTX);
        const float* pW = (const float*)(wsb + WS_PARTW);
        float a = fmaxf(fmaxf(pX[tid], pX[tid + 64]), fmaxf(pX[tid + 128], pX[tid + 192]));
        float b = fmaxf(fmaxf(pW[tid], pW[tid + 64]), fmaxf(pW[tid + 128], pW[tid + 192]));
        #pragma unroll
        for (int o = 32; o > 0; o >>= 1) {
            a = fmaxf(a, __shfl_down(a, o, 64));
            b = fmaxf(b, __shfl_down(b, o, 64));
        }
        if (tid == 0) { scS[0] = a / 127.f; scS[1] = b / 127.f; }
    }
    // copy pre-converted int16 LUT: 8192 uint4
    {
        const uint4* g = (const uint4*)(wsb + WS_LUT16);
        uint4* d = (uint4*)lutS;
        #pragma unroll
        for (int it = 0; it < 11; ++it) {
            int i = tid + it * NTH;
            if (i < 8192) d[i] = g[i];
        }
    }
    __syncthreads();
    const float sx = scS[0], sw = scS[1];

    // quantize this block's 4 x-rows, pack 4 rows per k into one dword
    {
        unsigned pk = 0;
        #pragma unroll
        for (int r = 0; r < 4; ++r) {
            float q = rintf(x[(row0 + r) * K + tid] / sx);
            q = fminf(fmaxf(q, -127.f), 127.f);
            pk |= ((unsigned)((int)q + 128)) << (r * 8);
        }
        xiS[tid] = pk;
    }
    __syncthreads();

    const int kp = tid / 192;        // wave-uniform (192 = 3 waves)
    const int j  = tid - kp * 192;
    const int cw = col0 + j;
    const int c0 = kp * 48;
    const unsigned* wP = (const unsigned*)(wsb + WS_WP);
    const uint4* xiS4 = (const uint4*)xiS;

    int acc0 = 0, acc1 = 0, acc2 = 0, acc3 = 0;
    unsigned wv = wP[c0 * 768 + cw];     // coalesced: lanes = consecutive j
    uint4    xv = xiS4[c0];              // wave-uniform broadcast
    for (int c = 0; c < 48; ++c) {
        int cn = (c + 1 < 48) ? (c + 1) : 47;     // depth-1 prefetch
        unsigned wv_n = wP[(c0 + cn) * 768 + cw];
        uint4    xv_n = xiS4[c0 + cn];
        #pragma unroll
        for (int u = 0; u < 4; ++u) {
            unsigned xd = (&xv.x)[u];
            unsigned wb = (wv >> (u * 8)) & 255u;
            acc0 += lutS[((xd & 255u) << 8) + wb];
            acc1 += lutS[(((xd >> 8) & 255u) << 8) + wb];
            acc2 += lutS[(((xd >> 16) & 255u) << 8) + wb];
            acc3 += lutS[((xd >> 24) << 8) + wb];
        }
        wv = wv_n; xv = xv_n;
    }

    red[tid * 4 + 0] = acc0;
    red[tid * 4 + 1] = acc1;
    red[tid * 4 + 2] = acc2;
    red[tid * 4 + 3] = acc3;
    __syncthreads();
    // thread (kp, j) emits output row (row0+kp), col cw
    int s = red[(0 * 192 + j) * 4 + kp] + red[(1 * 192 + j) * 4 + kp]
          + red[(2 * 192 + j) * 4 + kp] + red[(3 * 192 + j) * 4 + kp];
    out[(row0 + kp) * N + cw] = (float)s * (sx * sw) + bias[cw];
}

extern "C" void kernel_launch(void* const* d_in, const int* in_sizes, int n_in,
                              void* d_out, int out_size, void* d_ws, size_t ws_size,
                              hipStream_t stream) {
    const float* x    = (const float*)d_in[0];
    const float* w    = (const float*)d_in[1];
    const float* bias = (const float*)d_in[2];
    const int*   lut  = (const int*)d_in[3];
    float* out = (float*)d_out;
    unsigned char* wsb = (unsigned char*)d_ws;

    absmax_lut_kernel<<<256, 256, 0, stream>>>(x, w, lut, wsb);
    wquant_kernel<<<288, 512, 0, stream>>>(w, wsb);
    hipFuncSetAttribute((const void*)lutmm_kernel,
                        hipFuncAttributeMaxDynamicSharedMemorySize, SMEM_BYTES);
    lutmm_kernel<<<dim3(M / TI, N / TJ), NTH, SMEM_BYTES, stream>>>(
        x, bias, wsb, out);
}